// Round 1
// baseline (215.770 us; speedup 1.0000x reference)
//
#include <hip/hip_runtime.h>

typedef __attribute__((ext_vector_type(8))) short bf16x8;
typedef __attribute__((ext_vector_type(4))) float f32x4;

__device__ __forceinline__ float bf2f(unsigned short u) {
  return __uint_as_float(((unsigned int)u) << 16);
}
__device__ __forceinline__ unsigned short f2bf(float f) {
  unsigned int u = __float_as_uint(f);
  u += 0x7fffu + ((u >> 16) & 1u);
  return (unsigned short)(u >> 16);
}

// ---------------- workspace layout (bytes) ----------------
// x_pad bf16 [8][66][66][128]
constexpr size_t OFF_XPAD = 0;
constexpr size_t SZ_XPAD  = (size_t)8 * 66 * 66 * 128 * 2;        // 8,921,088
// wB bf16 [9][16][256][8]  (main conv weights, B-frag layout)
constexpr size_t OFF_WB   = OFF_XPAD + SZ_XPAD;
constexpr size_t SZ_WB    = (size_t)9 * 16 * 256 * 8 * 2;         // 589,824
// wS bf16 [16][256][8]     (shortcut 1x1 weights)
constexpr size_t OFF_WS2  = OFF_WB + SZ_WB;
constexpr size_t SZ_WS2   = (size_t)16 * 256 * 8 * 2;             // 65,536
// wO bf16 [9][16][32][8]   (offset conv weights, n padded 18->32)
constexpr size_t OFF_WO   = OFF_WS2 + SZ_WS2;
constexpr size_t SZ_WO    = (size_t)9 * 16 * 32 * 8 * 2;          // 73,728
// offsets fp32 [32768][18]
constexpr size_t OFF_OFFS = OFF_WO + SZ_WO;
constexpr size_t SZ_OFFS  = (size_t)32768 * 18 * 4;               // 2,359,296
// y_main fp32 [32768][256]
constexpr size_t OFF_YM   = OFF_OFFS + SZ_OFFS;
constexpr size_t SZ_YM    = (size_t)32768 * 256 * 4;              // 33,554,432
// partials fp32 [512][256][2]
constexpr size_t OFF_PART = OFF_YM + SZ_YM;
constexpr size_t SZ_PART  = (size_t)512 * 256 * 2 * 4;            // 1,048,576
// stats fp32 [256][2]  (A = gamma*invstd, B = beta - mean*A)
constexpr size_t OFF_STAT = OFF_PART + SZ_PART;

// ---------------- x: NCHW fp32 -> NHWC bf16 zero-padded ----------------
__global__ __launch_bounds__(256) void k_prep_x(const float* __restrict__ x,
                                                unsigned short* __restrict__ xp) {
  int blk = blockIdx.x;               // 512 = b*64 + h
  int b = blk >> 6, h = blk & 63;
  int t = threadIdx.x;
  __shared__ float tile[16][66];
  for (int cc = 0; cc < 8; ++cc) {
    int c0 = cc * 16;
    int wr = t & 63, cl = t >> 6;
#pragma unroll
    for (int i = 0; i < 4; ++i) {
      int c = c0 + cl * 4 + i;
      tile[cl * 4 + i][wr] = x[(((size_t)b * 128 + c) * 64 + h) * 64 + wr];
    }
    __syncthreads();
    int ww = t >> 2, cq = t & 3;
    ushort4 u4;
    u4.x = f2bf(tile[cq * 4 + 0][ww]);
    u4.y = f2bf(tile[cq * 4 + 1][ww]);
    u4.z = f2bf(tile[cq * 4 + 2][ww]);
    u4.w = f2bf(tile[cq * 4 + 3][ww]);
    *(ushort4*)(xp + ((size_t)(b * 66 + h + 1) * 66 + (ww + 1)) * 128 + c0 + cq * 4) = u4;
    __syncthreads();
  }
}

// ---------------- weight packing ----------------
__global__ __launch_bounds__(256) void k_pack_w(const float* __restrict__ wdef,
                                                const float* __restrict__ wsc,
                                                const float* __restrict__ woff,
                                                unsigned short* __restrict__ wB,
                                                unsigned short* __restrict__ wS,
                                                unsigned short* __restrict__ wO) {
  int tid = blockIdx.x * 256 + threadIdx.x;
  if (tid < 294912) {
    int k8 = tid & 7, n = (tid >> 3) & 255, kb = (tid >> 11) & 15, tap = tid >> 15;
    int c = kb * 8 + k8;
    wB[tid] = f2bf(wdef[((size_t)n * 128 + c) * 9 + tap]);
  } else if (tid < 294912 + 32768) {
    int i = tid - 294912;
    int k8 = i & 7, n = (i >> 3) & 255, kb = i >> 11;
    wS[i] = f2bf(wsc[(size_t)n * 128 + kb * 8 + k8]);
  } else if (tid < 294912 + 32768 + 36864) {
    int i = tid - 327680;
    int k8 = i & 7, n = (i >> 3) & 31, kb = (i >> 8) & 15, tap = i >> 12;
    int c = kb * 8 + k8;
    wO[i] = f2bf(n < 18 ? woff[((size_t)n * 128 + c) * 9 + tap] : 0.f);
  }
}

// ---------------- offset conv (3x3, 128->18 padded to 32) via MFMA ----------------
__global__ __launch_bounds__(256) void k_offset(const unsigned short* __restrict__ xp,
                                                const unsigned short* __restrict__ wO,
                                                const float* __restrict__ boff,
                                                float* __restrict__ offs) {
  int blk = blockIdx.x;               // 512 = b*64 + h
  int b = blk >> 6, h = blk & 63;
  int t = threadIdx.x;
  int lane = t & 63, wid = t >> 6;    // 4 waves x 16 px
  int m = lane & 15, quad = lane >> 4;
  f32x4 acc0 = {0.f, 0.f, 0.f, 0.f}, acc1 = {0.f, 0.f, 0.f, 0.f};
  int px = wid * 16 + m;
  const unsigned short* xbase = xp + ((size_t)(b * 66 + h) * 66 + px) * 128 + quad * 8;
  for (int tap = 0; tap < 9; ++tap) {
    int ty = tap / 3, tx = tap % 3;
    const unsigned short* arow = xbase + (ty * 66 + tx) * 128;
#pragma unroll
    for (int kk = 0; kk < 4; ++kk) {
      bf16x8 a = *(const bf16x8*)(arow + kk * 32);
      const unsigned short* bb = wO + (size_t)(tap * 16 + kk * 4 + quad) * 32 * 8;
      bf16x8 b0 = *(const bf16x8*)(bb + m * 8);
      bf16x8 b1 = *(const bf16x8*)(bb + (16 + m) * 8);
      acc0 = __builtin_amdgcn_mfma_f32_16x16x32_bf16(a, b0, acc0, 0, 0, 0);
      acc1 = __builtin_amdgcn_mfma_f32_16x16x32_bf16(a, b1, acc1, 0, 0, 0);
    }
  }
#pragma unroll
  for (int r = 0; r < 4; ++r) {
    int pxs = wid * 16 + quad * 4 + r;
    int pg = blk * 64 + pxs;
    if (m < 18) offs[(size_t)pg * 18 + m] = acc0[r] + boff[m];
    int n1 = 16 + m;
    if (n1 < 18) offs[(size_t)pg * 18 + n1] = acc1[r] + boff[n1];
  }
}

// ---------------- main: deform-sample + 3x3 conv GEMM + BN partials ----------------
__global__ __launch_bounds__(512) void k_main(const unsigned short* __restrict__ xp,
                                              const unsigned short* __restrict__ wB,
                                              const float* __restrict__ offs,
                                              const float* __restrict__ bdef,
                                              float* __restrict__ ymain,
                                              float* __restrict__ partials) {
  int blk = blockIdx.x;               // 256 blocks: b = blk>>5, rows h0,h0+1
  int b = blk >> 5;
  int h0 = (blk & 31) * 2;
  int t = threadIdx.x;
  int lane = t & 63, wid = t >> 6;    // 8 waves
  int m = lane & 15, quad = lane >> 4;
  __shared__ unsigned short At[128 * 136];   // 128 px x 128 ch, stride 136 (16B aligned)

  f32x4 acc[4][4];
#pragma unroll
  for (int i = 0; i < 4; ++i)
#pragma unroll
    for (int j = 0; j < 4; ++j) acc[i][j] = (f32x4){0.f, 0.f, 0.f, 0.f};

  // sampling role: 128 px x 4 channel-groups of 32
  int spx = t & 127, cg = t >> 7;
  int sh = h0 + (spx >> 6), sw = spx & 63;
  int spg = blk * 128 + spx;
  // mfma role
  int mbase = (wid >> 2) * 64;        // px half
  int nb = (wid & 3) * 64;            // out-channel range

  for (int tap = 0; tap < 9; ++tap) {
    // ---- bilinear sampling into LDS A-tile ----
    int ky = tap / 3 - 1, kx = tap % 3 - 1;
    float ody = offs[(size_t)spg * 18 + tap * 2];
    float odx = offs[(size_t)spg * 18 + tap * 2 + 1];
    float py = (float)(sh + ky) + ody;
    float pxf = (float)(sw + kx) + odx;
    float y0f = floorf(py), x0f = floorf(pxf);
    float fy = py - y0f, fx = pxf - x0f;
    int iy0 = (int)y0f, ix0 = (int)x0f;
    float wgt[4];
    const unsigned short* p[4];
#pragma unroll
    for (int j = 0; j < 4; ++j) {
      int iy = iy0 + (j >> 1), ix = ix0 + (j & 1);
      float wy = (j >> 1) ? fy : 1.f - fy;
      float wx = (j & 1) ? fx : 1.f - fx;
      bool valid = (iy >= 0) && (iy < 64) && (ix >= 0) && (ix < 64);
      int iyc = min(max(iy, 0), 63), ixc = min(max(ix, 0), 63);
      wgt[j] = valid ? wy * wx : 0.f;
      p[j] = xp + ((size_t)(b * 66 + iyc + 1) * 66 + (ixc + 1)) * 128 + cg * 32;
    }
    unsigned short* adst = At + spx * 136 + cg * 32;
#pragma unroll
    for (int ccs = 0; ccs < 4; ++ccs) {
      bf16x8 v0 = *(const bf16x8*)(p[0] + ccs * 8);
      bf16x8 v1 = *(const bf16x8*)(p[1] + ccs * 8);
      bf16x8 v2 = *(const bf16x8*)(p[2] + ccs * 8);
      bf16x8 v3 = *(const bf16x8*)(p[3] + ccs * 8);
      bf16x8 o;
#pragma unroll
      for (int j = 0; j < 8; ++j) {
        float s = wgt[0] * bf2f((unsigned short)v0[j])
                + wgt[1] * bf2f((unsigned short)v1[j])
                + wgt[2] * bf2f((unsigned short)v2[j])
                + wgt[3] * bf2f((unsigned short)v3[j]);
        o[j] = (short)f2bf(s);
      }
      *(bf16x8*)(adst + ccs * 8) = o;
    }
    __syncthreads();
    // ---- MFMA: this tap's K=128 slab ----
#pragma unroll
    for (int kk = 0; kk < 4; ++kk) {
      bf16x8 af[4];
#pragma unroll
      for (int ms = 0; ms < 4; ++ms)
        af[ms] = *(const bf16x8*)(At + (mbase + ms * 16 + m) * 136 + kk * 32 + quad * 8);
#pragma unroll
      for (int ns = 0; ns < 4; ++ns) {
        bf16x8 bfr = *(const bf16x8*)(wB + ((size_t)(tap * 16 + kk * 4 + quad) * 256 + nb + ns * 16 + m) * 8);
#pragma unroll
        for (int ms = 0; ms < 4; ++ms)
          acc[ms][ns] = __builtin_amdgcn_mfma_f32_16x16x32_bf16(af[ms], bfr, acc[ms][ns], 0, 0, 0);
      }
    }
    __syncthreads();
  }

  // ---- epilogue: bias, store y_main, per-channel partial sums ----
  int half = wid >> 2;
#pragma unroll
  for (int ns = 0; ns < 4; ++ns) {
    int n = nb + ns * 16 + m;
    float bias = bdef[n];
    float s = 0.f, q = 0.f;
#pragma unroll
    for (int ms = 0; ms < 4; ++ms) {
#pragma unroll
      for (int r = 0; r < 4; ++r) {
        int px = mbase + ms * 16 + quad * 4 + r;
        float v = acc[ms][ns][r] + bias;
        ymain[(size_t)(blk * 128 + px) * 256 + n] = v;
        s += v;
        q += v * v;
      }
    }
    s += __shfl_xor(s, 16); s += __shfl_xor(s, 32);
    q += __shfl_xor(q, 16); q += __shfl_xor(q, 32);
    if (quad == 0) {
      int row = blk * 2 + half;
      partials[((size_t)row * 256 + n) * 2 + 0] = s;
      partials[((size_t)row * 256 + n) * 2 + 1] = q;
    }
  }
}

// ---------------- BN stats reduce ----------------
__global__ __launch_bounds__(64) void k_stats(const float* __restrict__ partials,
                                              const float* __restrict__ gamma,
                                              const float* __restrict__ beta,
                                              float* __restrict__ stats) {
  int ch = blockIdx.x;                // 256
  int L = threadIdx.x;                // 64
  float s = 0.f, q = 0.f;
#pragma unroll
  for (int i = 0; i < 8; ++i) {
    int row = i * 64 + L;
    s += partials[((size_t)row * 256 + ch) * 2 + 0];
    q += partials[((size_t)row * 256 + ch) * 2 + 1];
  }
#pragma unroll
  for (int d = 1; d < 64; d <<= 1) { s += __shfl_xor(s, d); q += __shfl_xor(q, d); }
  if (L == 0) {
    float mean = s * (1.f / 32768.f);
    float var = q * (1.f / 32768.f) - mean * mean;
    float inv = rsqrtf(var + 1e-5f);
    float A = gamma[ch] * inv;
    stats[ch * 2 + 0] = A;
    stats[ch * 2 + 1] = beta[ch] - mean * A;
  }
}

// ---------------- final: 1x1 shortcut MFMA + BN apply + ReLU + NCHW store ----------------
__global__ __launch_bounds__(256) void k_final(const unsigned short* __restrict__ xp,
                                               const unsigned short* __restrict__ wS,
                                               const float* __restrict__ ymain,
                                               const float* __restrict__ stats,
                                               const float* __restrict__ bsc,
                                               float* __restrict__ out) {
  int blk = blockIdx.x;               // 512 = b*64 + h
  int b = blk >> 6, h = blk & 63;
  int t = threadIdx.x;
  int lane = t & 63, wid = t >> 6;    // 4 waves x 64 out-ch
  int m = lane & 15, quad = lane >> 4;
  __shared__ float tr[128 * 65];
  f32x4 acc[4][4];
#pragma unroll
  for (int i = 0; i < 4; ++i)
#pragma unroll
    for (int j = 0; j < 4; ++j) acc[i][j] = (f32x4){0.f, 0.f, 0.f, 0.f};
  const unsigned short* xrow = xp + ((size_t)(b * 66 + h + 1) * 66 + 1) * 128;
  int nb = wid * 64;
#pragma unroll
  for (int kk = 0; kk < 4; ++kk) {
    bf16x8 af[4];
#pragma unroll
    for (int ms = 0; ms < 4; ++ms)
      af[ms] = *(const bf16x8*)(xrow + (ms * 16 + m) * 128 + kk * 32 + quad * 8);
#pragma unroll
    for (int ns = 0; ns < 4; ++ns) {
      bf16x8 bfr = *(const bf16x8*)(wS + ((size_t)(kk * 4 + quad) * 256 + nb + ns * 16 + m) * 8);
#pragma unroll
      for (int ms = 0; ms < 4; ++ms)
        acc[ms][ns] = __builtin_amdgcn_mfma_f32_16x16x32_bf16(af[ms], bfr, acc[ms][ns], 0, 0, 0);
    }
  }
  for (int pass = 0; pass < 2; ++pass) {
    if ((wid >> 1) == pass) {
#pragma unroll
      for (int ns = 0; ns < 4; ++ns) {
        int n = nb + ns * 16 + m;
        float A = stats[n * 2], Bc = stats[n * 2 + 1];
        float bs = bsc[n];
#pragma unroll
        for (int ms = 0; ms < 4; ++ms) {
#pragma unroll
          for (int r = 0; r < 4; ++r) {
            int px = ms * 16 + quad * 4 + r;
            float ym = ymain[(size_t)(blk * 64 + px) * 256 + n];
            float v = ym * A + Bc + acc[ms][ns][r] + bs;
            tr[(n - pass * 128) * 65 + px] = fmaxf(v, 0.f);
          }
        }
      }
    }
    __syncthreads();
    int ww = t & 63, ng = t >> 6;
#pragma unroll 4
    for (int i = 0; i < 32; ++i) {
      int nl = ng * 32 + i;
      int n = pass * 128 + nl;
      out[((size_t)(b * 256 + n) * 64 + h) * 64 + ww] = tr[nl * 65 + ww];
    }
    __syncthreads();
  }
}

extern "C" void kernel_launch(void* const* d_in, const int* in_sizes, int n_in,
                              void* d_out, int out_size, void* d_ws, size_t ws_size,
                              hipStream_t stream) {
  const float* x     = (const float*)d_in[0];
  const float* w_off = (const float*)d_in[1];
  const float* b_off = (const float*)d_in[2];
  const float* w_def = (const float*)d_in[3];
  const float* b_def = (const float*)d_in[4];
  const float* gamma = (const float*)d_in[5];
  const float* beta  = (const float*)d_in[6];
  const float* w_sc  = (const float*)d_in[7];
  const float* b_sc  = (const float*)d_in[8];
  float* out = (float*)d_out;

  char* ws = (char*)d_ws;
  unsigned short* xpad  = (unsigned short*)(ws + OFF_XPAD);
  unsigned short* wB    = (unsigned short*)(ws + OFF_WB);
  unsigned short* wS    = (unsigned short*)(ws + OFF_WS2);
  unsigned short* wO    = (unsigned short*)(ws + OFF_WO);
  float* offs           = (float*)(ws + OFF_OFFS);
  float* ymain          = (float*)(ws + OFF_YM);
  float* partials       = (float*)(ws + OFF_PART);
  float* stats          = (float*)(ws + OFF_STAT);

  hipMemsetAsync(xpad, 0, SZ_XPAD, stream);
  k_prep_x<<<512, 256, 0, stream>>>(x, xpad);
  k_pack_w<<<1424, 256, 0, stream>>>(w_def, w_sc, w_off, wB, wS, wO);
  k_offset<<<512, 256, 0, stream>>>(xpad, wO, b_off, offs);
  k_main<<<256, 512, 0, stream>>>(xpad, wB, offs, b_def, ymain, partials);
  k_stats<<<256, 64, 0, stream>>>(partials, gamma, beta, stats);
  k_final<<<512, 256, 0, stream>>>(xpad, wS, ymain, stats, b_sc, out);
}

// Round 2
// 182.852 us; speedup vs baseline: 1.1800x; 1.1800x over previous
//
#include <hip/hip_runtime.h>

typedef __attribute__((ext_vector_type(8))) short bf16x8;
typedef __attribute__((ext_vector_type(4))) float f32x4;

__device__ __forceinline__ float bf2f(unsigned short u) {
  return __uint_as_float(((unsigned int)u) << 16);
}
__device__ __forceinline__ unsigned short f2bf(float f) {
  unsigned int u = __float_as_uint(f);
  u += 0x7fffu + ((u >> 16) & 1u);
  return (unsigned short)(u >> 16);
}

// ---------------- workspace layout (bytes) ----------------
constexpr size_t OFF_XPAD = 0;
constexpr size_t SZ_XPAD  = (size_t)8 * 66 * 66 * 128 * 2;        // 8,921,088
constexpr size_t OFF_WB   = OFF_XPAD + SZ_XPAD;
constexpr size_t SZ_WB    = (size_t)9 * 16 * 256 * 8 * 2;         // 589,824
constexpr size_t OFF_WS2  = OFF_WB + SZ_WB;
constexpr size_t SZ_WS2   = (size_t)16 * 256 * 8 * 2;             // 65,536
constexpr size_t OFF_WO   = OFF_WS2 + SZ_WS2;
constexpr size_t SZ_WO    = (size_t)9 * 16 * 32 * 8 * 2;          // 73,728
// offsets fp32 TRANSPOSED [9][32768][2] for coalesced per-tap reads
constexpr size_t OFF_OFFS = OFF_WO + SZ_WO;
constexpr size_t SZ_OFFS  = (size_t)9 * 32768 * 2 * 4;            // 2,359,296
// y_main bf16 [32768][256]
constexpr size_t OFF_YM   = OFF_OFFS + SZ_OFFS;
constexpr size_t SZ_YM    = (size_t)32768 * 256 * 2;              // 16,777,216
constexpr size_t OFF_PART = OFF_YM + SZ_YM;
constexpr size_t SZ_PART  = (size_t)512 * 256 * 2 * 4;            // 1,048,576
constexpr size_t OFF_STAT = OFF_PART + SZ_PART;

// ---------------- x: NCHW fp32 -> NHWC bf16 zero-padded ----------------
__global__ __launch_bounds__(256) void k_prep_x(const float* __restrict__ x,
                                                unsigned short* __restrict__ xp) {
  int blk = blockIdx.x;               // 512 = b*64 + h
  int b = blk >> 6, h = blk & 63;
  int t = threadIdx.x;
  __shared__ float tile[16][66];
  for (int cc = 0; cc < 8; ++cc) {
    int c0 = cc * 16;
    int wr = t & 63, cl = t >> 6;
#pragma unroll
    for (int i = 0; i < 4; ++i) {
      int c = c0 + cl * 4 + i;
      tile[cl * 4 + i][wr] = x[(((size_t)b * 128 + c) * 64 + h) * 64 + wr];
    }
    __syncthreads();
    int ww = t >> 2, cq = t & 3;
    ushort4 u4;
    u4.x = f2bf(tile[cq * 4 + 0][ww]);
    u4.y = f2bf(tile[cq * 4 + 1][ww]);
    u4.z = f2bf(tile[cq * 4 + 2][ww]);
    u4.w = f2bf(tile[cq * 4 + 3][ww]);
    *(ushort4*)(xp + ((size_t)(b * 66 + h + 1) * 66 + (ww + 1)) * 128 + c0 + cq * 4) = u4;
    __syncthreads();
  }
}

// ---------------- weight packing ----------------
__global__ __launch_bounds__(256) void k_pack_w(const float* __restrict__ wdef,
                                                const float* __restrict__ wsc,
                                                const float* __restrict__ woff,
                                                unsigned short* __restrict__ wB,
                                                unsigned short* __restrict__ wS,
                                                unsigned short* __restrict__ wO) {
  int tid = blockIdx.x * 256 + threadIdx.x;
  if (tid < 294912) {
    int k8 = tid & 7, n = (tid >> 3) & 255, kb = (tid >> 11) & 15, tap = tid >> 15;
    int c = kb * 8 + k8;
    wB[tid] = f2bf(wdef[((size_t)n * 128 + c) * 9 + tap]);
  } else if (tid < 294912 + 32768) {
    int i = tid - 294912;
    int k8 = i & 7, n = (i >> 3) & 255, kb = i >> 11;
    wS[i] = f2bf(wsc[(size_t)n * 128 + kb * 8 + k8]);
  } else if (tid < 294912 + 32768 + 36864) {
    int i = tid - 327680;
    int k8 = i & 7, n = (i >> 3) & 31, kb = (i >> 8) & 15, tap = i >> 12;
    int c = kb * 8 + k8;
    wO[i] = f2bf(n < 18 ? woff[((size_t)n * 128 + c) * 9 + tap] : 0.f);
  }
}

// ---------------- offset conv (3x3, 128->18 padded to 32) via MFMA ----------------
// writes TRANSPOSED offs[9][32768][2]
__global__ __launch_bounds__(256) void k_offset(const unsigned short* __restrict__ xp,
                                                const unsigned short* __restrict__ wO,
                                                const float* __restrict__ boff,
                                                float* __restrict__ offs) {
  int blk = blockIdx.x;               // 512 = b*64 + h
  int b = blk >> 6, h = blk & 63;
  int t = threadIdx.x;
  int lane = t & 63, wid = t >> 6;    // 4 waves x 16 px
  int m = lane & 15, quad = lane >> 4;
  f32x4 acc0 = {0.f, 0.f, 0.f, 0.f}, acc1 = {0.f, 0.f, 0.f, 0.f};
  int px = wid * 16 + m;
  const unsigned short* xbase = xp + ((size_t)(b * 66 + h) * 66 + px) * 128 + quad * 8;
  for (int tap = 0; tap < 9; ++tap) {
    int ty = tap / 3, tx = tap % 3;
    const unsigned short* arow = xbase + (ty * 66 + tx) * 128;
#pragma unroll
    for (int kk = 0; kk < 4; ++kk) {
      bf16x8 a = *(const bf16x8*)(arow + kk * 32);
      const unsigned short* bb = wO + (size_t)(tap * 16 + kk * 4 + quad) * 32 * 8;
      bf16x8 b0 = *(const bf16x8*)(bb + m * 8);
      bf16x8 b1 = *(const bf16x8*)(bb + (16 + m) * 8);
      acc0 = __builtin_amdgcn_mfma_f32_16x16x32_bf16(a, b0, acc0, 0, 0, 0);
      acc1 = __builtin_amdgcn_mfma_f32_16x16x32_bf16(a, b1, acc1, 0, 0, 0);
    }
  }
#pragma unroll
  for (int r = 0; r < 4; ++r) {
    int pxs = wid * 16 + quad * 4 + r;
    int pg = blk * 64 + pxs;
    // acc0 holds n = m in [0,16): tap = n>>1, comp = n&1
    offs[((size_t)(m >> 1) * 32768 + pg) * 2 + (m & 1)] = acc0[r] + boff[m];
    // acc1 holds n = 16+m; valid for n < 18 -> m < 2 (tap 8)
    if (m < 2)
      offs[((size_t)8 * 32768 + pg) * 2 + m] = acc1[r] + boff[16 + m];
  }
}

// ---------------- main: deform-sample + 3x3 conv GEMM + BN partials ----------------
// 512 blocks x 256 thr; 64-px tile; double-buffered LDS; pipelined sampling.
__global__ __launch_bounds__(256) void k_main(const unsigned short* __restrict__ xp,
                                              const unsigned short* __restrict__ wB,
                                              const float* __restrict__ offs,
                                              const float* __restrict__ bdef,
                                              unsigned short* __restrict__ ymain,
                                              float* __restrict__ partials) {
  int blk = blockIdx.x;               // 512 = b*64 + h
  int b = blk >> 6, h = blk & 63;
  int t = threadIdx.x;
  int lane = t & 63, wid = t >> 6;    // 4 waves
  int m = lane & 15, quad = lane >> 4;
  __shared__ __align__(16) unsigned short At[2][64 * 136];  // 2 x 17408 B

  f32x4 acc[4][4];
#pragma unroll
  for (int i = 0; i < 4; ++i)
#pragma unroll
    for (int j = 0; j < 4; ++j) acc[i][j] = (f32x4){0.f, 0.f, 0.f, 0.f};

  // sampling role: 64 px x 4 channel-groups of 32 ch
  int spx = t & 63, cg = t >> 6;
  int pg = blk * 64 + spx;
  // preload all 9 offset pairs (coalesced: consecutive lanes -> consecutive pg)
  float2 offv[9];
#pragma unroll
  for (int tap = 0; tap < 9; ++tap)
    offv[tap] = ((const float2*)offs)[(size_t)tap * 32768 + pg];

  const unsigned short* xb_base = xp + (size_t)b * 66 * 66 * 128 + cg * 32;
  int nb = wid * 64;                  // mfma role: N range per wave, M=64 shared

  auto sample_prep = [&](int tap, float* wgt, const unsigned short** p) {
    int ky = tap / 3 - 1, kx = tap % 3 - 1;
    float py = (float)(h + ky) + offv[tap].x;
    float pxf = (float)(spx + kx) + offv[tap].y;
    float y0f = floorf(py), x0f = floorf(pxf);
    float fy = py - y0f, fx = pxf - x0f;
    int iy0 = (int)y0f, ix0 = (int)x0f;
#pragma unroll
    for (int j = 0; j < 4; ++j) {
      int iy = iy0 + (j >> 1), ix = ix0 + (j & 1);
      float wy = (j >> 1) ? fy : 1.f - fy;
      float wx = (j & 1) ? fx : 1.f - fx;
      bool valid = (iy >= 0) && (iy < 64) && (ix >= 0) && (ix < 64);
      int iyc = min(max(iy, 0), 63), ixc = min(max(ix, 0), 63);
      wgt[j] = valid ? wy * wx : 0.f;
      p[j] = xb_base + ((size_t)(iyc + 1) * 66 + (ixc + 1)) * 128;
    }
  };
  auto load_half = [&](const unsigned short** p, int c0, bf16x8 (*v)[4]) {
#pragma unroll
    for (int cc = 0; cc < 2; ++cc)
#pragma unroll
      for (int j = 0; j < 4; ++j)
        v[cc][j] = *(const bf16x8*)(p[j] + (c0 + cc) * 8);
  };
  auto store_half = [&](unsigned short* dst, int c0, const float* wgt, bf16x8 (*v)[4]) {
#pragma unroll
    for (int cc = 0; cc < 2; ++cc) {
      bf16x8 o;
#pragma unroll
      for (int j = 0; j < 8; ++j) {
        float s = fmaf(wgt[0], bf2f((unsigned short)v[cc][0][j]),
                  fmaf(wgt[1], bf2f((unsigned short)v[cc][1][j]),
                  fmaf(wgt[2], bf2f((unsigned short)v[cc][2][j]),
                       wgt[3] * bf2f((unsigned short)v[cc][3][j]))));
        o[j] = (short)f2bf(s);
      }
      *(bf16x8*)(dst + (c0 + cc) * 8) = o;
    }
  };
  auto mfma_half = [&](const unsigned short* buf, int tap, int kk0) {
#pragma unroll
    for (int kk = kk0; kk < kk0 + 2; ++kk) {
      bf16x8 af[4];
#pragma unroll
      for (int ms = 0; ms < 4; ++ms)
        af[ms] = *(const bf16x8*)(buf + (ms * 16 + m) * 136 + kk * 32 + quad * 8);
#pragma unroll
      for (int ns = 0; ns < 4; ++ns) {
        bf16x8 bfr = *(const bf16x8*)(wB + ((size_t)(tap * 16 + kk * 4 + quad) * 256 + nb + ns * 16 + m) * 8);
#pragma unroll
        for (int ms = 0; ms < 4; ++ms)
          acc[ms][ns] = __builtin_amdgcn_mfma_f32_16x16x32_bf16(af[ms], bfr, acc[ms][ns], 0, 0, 0);
      }
    }
  };

  // prologue: sample tap 0 into buf 0
  {
    float wgt[4]; const unsigned short* p[4]; bf16x8 v[2][4];
    sample_prep(0, wgt, p);
    unsigned short* dst = &At[0][spx * 136 + cg * 32];
    load_half(p, 0, v); store_half(dst, 0, wgt, v);
    load_half(p, 2, v); store_half(dst, 2, wgt, v);
  }
#pragma unroll
  for (int tap = 0; tap < 9; ++tap) {
    __syncthreads();
    const unsigned short* cur = At[tap & 1];
    unsigned short* dst = &At[(tap + 1) & 1][spx * 136 + cg * 32];
    if (tap < 8) {
      float wgt[4]; const unsigned short* p[4]; bf16x8 v[2][4];
      sample_prep(tap + 1, wgt, p);
      load_half(p, 0, v);           // gathers in flight...
      mfma_half(cur, tap, 0);       // ...hidden behind 32 MFMAs
      store_half(dst, 0, wgt, v);
      load_half(p, 2, v);
      mfma_half(cur, tap, 2);
      store_half(dst, 2, wgt, v);
    } else {
      mfma_half(cur, tap, 0);
      mfma_half(cur, tap, 2);
    }
  }

  // epilogue: bias, bf16 y_main store, per-channel partial sums
#pragma unroll
  for (int ns = 0; ns < 4; ++ns) {
    int n = nb + ns * 16 + m;
    float bias = bdef[n];
    float s = 0.f, q = 0.f;
#pragma unroll
    for (int ms = 0; ms < 4; ++ms) {
#pragma unroll
      for (int r = 0; r < 4; ++r) {
        int px = ms * 16 + quad * 4 + r;
        float v = acc[ms][ns][r] + bias;
        ymain[(size_t)(blk * 64 + px) * 256 + n] = f2bf(v);
        s += v;
        q += v * v;
      }
    }
    s += __shfl_xor(s, 16); s += __shfl_xor(s, 32);
    q += __shfl_xor(q, 16); q += __shfl_xor(q, 32);
    if (quad == 0) {
      partials[((size_t)blk * 256 + n) * 2 + 0] = s;
      partials[((size_t)blk * 256 + n) * 2 + 1] = q;
    }
  }
}

// ---------------- BN stats reduce ----------------
__global__ __launch_bounds__(64) void k_stats(const float* __restrict__ partials,
                                              const float* __restrict__ gamma,
                                              const float* __restrict__ beta,
                                              float* __restrict__ stats) {
  int ch = blockIdx.x;                // 256
  int L = threadIdx.x;                // 64
  float s = 0.f, q = 0.f;
#pragma unroll
  for (int i = 0; i < 8; ++i) {
    int row = i * 64 + L;
    s += partials[((size_t)row * 256 + ch) * 2 + 0];
    q += partials[((size_t)row * 256 + ch) * 2 + 1];
  }
#pragma unroll
  for (int d = 1; d < 64; d <<= 1) { s += __shfl_xor(s, d); q += __shfl_xor(q, d); }
  if (L == 0) {
    float mean = s * (1.f / 32768.f);
    float var = q * (1.f / 32768.f) - mean * mean;
    float inv = rsqrtf(var + 1e-5f);
    float A = gamma[ch] * inv;
    stats[ch * 2 + 0] = A;
    stats[ch * 2 + 1] = beta[ch] - mean * A;
  }
}

// ---------------- final: 1x1 shortcut MFMA + BN apply + ReLU + NCHW store ----------------
__global__ __launch_bounds__(256) void k_final(const unsigned short* __restrict__ xp,
                                               const unsigned short* __restrict__ wS,
                                               const unsigned short* __restrict__ ymain,
                                               const float* __restrict__ stats,
                                               const float* __restrict__ bsc,
                                               float* __restrict__ out) {
  int blk = blockIdx.x;               // 512 = b*64 + h
  int b = blk >> 6, h = blk & 63;
  int t = threadIdx.x;
  int lane = t & 63, wid = t >> 6;
  int m = lane & 15, quad = lane >> 4;
  __shared__ float tr[128 * 67];
  f32x4 acc[4][4];
#pragma unroll
  for (int i = 0; i < 4; ++i)
#pragma unroll
    for (int j = 0; j < 4; ++j) acc[i][j] = (f32x4){0.f, 0.f, 0.f, 0.f};
  const unsigned short* xrow = xp + ((size_t)(b * 66 + h + 1) * 66 + 1) * 128;
  int nb = wid * 64;
#pragma unroll
  for (int kk = 0; kk < 4; ++kk) {
    bf16x8 af[4];
#pragma unroll
    for (int ms = 0; ms < 4; ++ms)
      af[ms] = *(const bf16x8*)(xrow + (ms * 16 + m) * 128 + kk * 32 + quad * 8);
#pragma unroll
    for (int ns = 0; ns < 4; ++ns) {
      bf16x8 bfr = *(const bf16x8*)(wS + ((size_t)(kk * 4 + quad) * 256 + nb + ns * 16 + m) * 8);
#pragma unroll
      for (int ms = 0; ms < 4; ++ms)
        acc[ms][ns] = __builtin_amdgcn_mfma_f32_16x16x32_bf16(af[ms], bfr, acc[ms][ns], 0, 0, 0);
    }
  }
  for (int pass = 0; pass < 2; ++pass) {
    // phase A: waves owning this n-half park shortcut+bias into LDS
    if ((wid >> 1) == pass) {
#pragma unroll
      for (int ns = 0; ns < 4; ++ns) {
        int n = nb + ns * 16 + m;
        float bs = bsc[n];
        int nl = n - pass * 128;
#pragma unroll
        for (int ms = 0; ms < 4; ++ms)
#pragma unroll
          for (int r = 0; r < 4; ++r) {
            int px = ms * 16 + quad * 4 + r;
            tr[nl * 67 + px] = acc[ms][ns][r] + bs;
          }
      }
    }
    __syncthreads();
    // phase B: coalesced bf16 ymain read + BN + ReLU, in place
    {
      int nl = t & 127, g = t >> 7;
      int n = pass * 128 + nl;
      float A = stats[n * 2], Bc = stats[n * 2 + 1];
#pragma unroll 8
      for (int i = 0; i < 32; ++i) {
        int px = g * 32 + i;
        float ym = bf2f(ymain[(size_t)(blk * 64 + px) * 256 + n]);
        float* pt = &tr[nl * 67 + px];
        *pt = fmaxf(fmaf(ym, A, Bc) + *pt, 0.f);
      }
    }
    __syncthreads();
    // phase C: transpose-store, coalesced in w
    {
      int ww = t & 63, ng = t >> 6;
#pragma unroll 8
      for (int i = 0; i < 32; ++i) {
        int nl = ng * 32 + i;
        out[((size_t)(b * 256 + pass * 128 + nl) * 64 + h) * 64 + ww] = tr[nl * 67 + ww];
      }
    }
    __syncthreads();
  }
}

extern "C" void kernel_launch(void* const* d_in, const int* in_sizes, int n_in,
                              void* d_out, int out_size, void* d_ws, size_t ws_size,
                              hipStream_t stream) {
  const float* x     = (const float*)d_in[0];
  const float* w_off = (const float*)d_in[1];
  const float* b_off = (const float*)d_in[2];
  const float* w_def = (const float*)d_in[3];
  const float* b_def = (const float*)d_in[4];
  const float* gamma = (const float*)d_in[5];
  const float* beta  = (const float*)d_in[6];
  const float* w_sc  = (const float*)d_in[7];
  const float* b_sc  = (const float*)d_in[8];
  float* out = (float*)d_out;

  char* ws = (char*)d_ws;
  unsigned short* xpad  = (unsigned short*)(ws + OFF_XPAD);
  unsigned short* wB    = (unsigned short*)(ws + OFF_WB);
  unsigned short* wS    = (unsigned short*)(ws + OFF_WS2);
  unsigned short* wO    = (unsigned short*)(ws + OFF_WO);
  float* offs           = (float*)(ws + OFF_OFFS);
  unsigned short* ymain = (unsigned short*)(ws + OFF_YM);
  float* partials       = (float*)(ws + OFF_PART);
  float* stats          = (float*)(ws + OFF_STAT);

  hipMemsetAsync(xpad, 0, SZ_XPAD, stream);
  k_prep_x<<<512, 256, 0, stream>>>(x, xpad);
  k_pack_w<<<1424, 256, 0, stream>>>(w_def, w_sc, w_off, wB, wS, wO);
  k_offset<<<512, 256, 0, stream>>>(xpad, wO, b_off, offs);
  k_main<<<512, 256, 0, stream>>>(xpad, wB, offs, b_def, ymain, partials);
  k_stats<<<256, 64, 0, stream>>>(partials, gamma, beta, stats);
  k_final<<<512, 256, 0, stream>>>(xpad, wS, ymain, stats, b_sc, out);
}

// Round 3
// 162.150 us; speedup vs baseline: 1.3307x; 1.1277x over previous
//
#include <hip/hip_runtime.h>

typedef __attribute__((ext_vector_type(8))) short bf16x8;
typedef __attribute__((ext_vector_type(4))) float f32x4;

__device__ __forceinline__ float bf2f(unsigned short u) {
  return __uint_as_float(((unsigned int)u) << 16);
}
__device__ __forceinline__ unsigned short f2bf(float f) {
  unsigned int u = __float_as_uint(f);
  u += 0x7fffu + ((u >> 16) & 1u);
  return (unsigned short)(u >> 16);
}

// ---------------- workspace layout (bytes) ----------------
constexpr size_t OFF_XPAD = 0;
constexpr size_t SZ_XPAD  = (size_t)8 * 66 * 66 * 128 * 2;        // 8,921,088
constexpr size_t OFF_WB   = OFF_XPAD + SZ_XPAD;
constexpr size_t SZ_WB    = (size_t)9 * 16 * 256 * 8 * 2;         // 589,824
constexpr size_t OFF_WS2  = OFF_WB + SZ_WB;
constexpr size_t SZ_WS2   = (size_t)16 * 256 * 8 * 2;             // 65,536
constexpr size_t OFF_WO   = OFF_WS2 + SZ_WS2;
constexpr size_t SZ_WO    = (size_t)9 * 16 * 32 * 8 * 2;          // 73,728
// y_main bf16 [32768][256]
constexpr size_t OFF_YM   = OFF_WO + SZ_WO;
constexpr size_t SZ_YM    = (size_t)32768 * 256 * 2;              // 16,777,216
constexpr size_t OFF_PART = OFF_YM + SZ_YM;
constexpr size_t SZ_PART  = (size_t)512 * 256 * 2 * 4;            // 1,048,576
constexpr size_t OFF_STAT = OFF_PART + SZ_PART;

// ---------------- x: NCHW fp32 -> NHWC bf16 zero-padded ----------------
__global__ __launch_bounds__(256) void k_prep_x(const float* __restrict__ x,
                                                unsigned short* __restrict__ xp) {
  int blk = blockIdx.x;               // 512 = b*64 + h
  int b = blk >> 6, h = blk & 63;
  int t = threadIdx.x;
  __shared__ float tile[16][66];
  for (int cc = 0; cc < 8; ++cc) {
    int c0 = cc * 16;
    int wr = t & 63, cl = t >> 6;
#pragma unroll
    for (int i = 0; i < 4; ++i) {
      int c = c0 + cl * 4 + i;
      tile[cl * 4 + i][wr] = x[(((size_t)b * 128 + c) * 64 + h) * 64 + wr];
    }
    __syncthreads();
    int ww = t >> 2, cq = t & 3;
    ushort4 u4;
    u4.x = f2bf(tile[cq * 4 + 0][ww]);
    u4.y = f2bf(tile[cq * 4 + 1][ww]);
    u4.z = f2bf(tile[cq * 4 + 2][ww]);
    u4.w = f2bf(tile[cq * 4 + 3][ww]);
    *(ushort4*)(xp + ((size_t)(b * 66 + h + 1) * 66 + (ww + 1)) * 128 + c0 + cq * 4) = u4;
    __syncthreads();
  }
}

// ---------------- weight packing ----------------
__global__ __launch_bounds__(256) void k_pack_w(const float* __restrict__ wdef,
                                                const float* __restrict__ wsc,
                                                const float* __restrict__ woff,
                                                unsigned short* __restrict__ wB,
                                                unsigned short* __restrict__ wS,
                                                unsigned short* __restrict__ wO) {
  int tid = blockIdx.x * 256 + threadIdx.x;
  if (tid < 294912) {
    int k8 = tid & 7, n = (tid >> 3) & 255, kb = (tid >> 11) & 15, tap = tid >> 15;
    int c = kb * 8 + k8;
    wB[tid] = f2bf(wdef[((size_t)n * 128 + c) * 9 + tap]);
  } else if (tid < 294912 + 32768) {
    int i = tid - 294912;
    int k8 = i & 7, n = (i >> 3) & 255, kb = i >> 11;
    wS[i] = f2bf(wsc[(size_t)n * 128 + kb * 8 + k8]);
  } else if (tid < 294912 + 32768 + 36864) {
    int i = tid - 327680;
    int k8 = i & 7, n = (i >> 3) & 31, kb = (i >> 8) & 15, tap = i >> 12;
    int c = kb * 8 + k8;
    wO[i] = f2bf(n < 18 ? woff[((size_t)n * 128 + c) * 9 + tap] : 0.f);
  }
}

// ---------------- main: offset conv + deform-sample + 3x3 conv GEMM + BN partials ----------------
// 512 blocks x 256 thr (4 waves); 64-px row tile; double-buffered LDS; coalesced gathers.
__global__ __launch_bounds__(256) void k_main(const unsigned short* __restrict__ xp,
                                              const unsigned short* __restrict__ wB,
                                              const unsigned short* __restrict__ wO,
                                              const float* __restrict__ boff,
                                              const float* __restrict__ bdef,
                                              unsigned short* __restrict__ ymain,
                                              float* __restrict__ partials) {
  int blk = blockIdx.x;               // 512 = b*64 + h
  int b = blk >> 6, h = blk & 63;
  int t = threadIdx.x;
  int lane = t & 63, wid = t >> 6;    // 4 waves
  int m = lane & 15, quad = lane >> 4;
  __shared__ __align__(16) unsigned short At[2][64 * 136];  // 2 x 17408 B
  __shared__ float offsL[9][64][2];                          // 4608 B

  // ---- phase 0: inline offset conv (this row's 18 offsets -> LDS) ----
  {
    f32x4 a0 = {0.f, 0.f, 0.f, 0.f}, a1 = {0.f, 0.f, 0.f, 0.f};
    int px = wid * 16 + m;
    const unsigned short* xbase = xp + ((size_t)(b * 66 + h) * 66 + px) * 128 + quad * 8;
    for (int tap = 0; tap < 9; ++tap) {
      const unsigned short* arow = xbase + ((tap / 3) * 66 + (tap % 3)) * 128;
#pragma unroll
      for (int kk = 0; kk < 4; ++kk) {
        bf16x8 a = *(const bf16x8*)(arow + kk * 32);
        const unsigned short* bb = wO + (size_t)(tap * 16 + kk * 4 + quad) * 256;
        bf16x8 b0 = *(const bf16x8*)(bb + m * 8);
        bf16x8 b1 = *(const bf16x8*)(bb + (16 + m) * 8);
        a0 = __builtin_amdgcn_mfma_f32_16x16x32_bf16(a, b0, a0, 0, 0, 0);
        a1 = __builtin_amdgcn_mfma_f32_16x16x32_bf16(a, b1, a1, 0, 0, 0);
      }
    }
#pragma unroll
    for (int r = 0; r < 4; ++r) {
      int pxs = wid * 16 + quad * 4 + r;
      offsL[m >> 1][pxs][m & 1] = a0[r] + boff[m];   // n=m in [0,16): tap=n>>1, comp=n&1
      if (m < 2) offsL[8][pxs][m] = a1[r] + boff[16 + m];
    }
  }
  __syncthreads();

  f32x4 acc[4][4];
#pragma unroll
  for (int i = 0; i < 4; ++i)
#pragma unroll
    for (int j = 0; j < 4; ++j) acc[i][j] = (f32x4){0.f, 0.f, 0.f, 0.f};

  // sampling role: thread = px_s*4 + sub; 4 consecutive lanes cover one 64B line
  int px_s = t >> 2, sub = t & 3;
  const unsigned short* xb_base = xp + (size_t)b * 66 * 66 * 128;
  int nb = wid * 64;                  // mfma role: N range per wave, M=64 shared

  auto sample_prep = [&](int tap, float* wgt, const unsigned short** p) {
    float2 ov = *(const float2*)&offsL[tap][px_s][0];
    int ky = tap / 3 - 1, kx = tap % 3 - 1;
    float py = (float)(h + ky) + ov.x;
    float pxf = (float)(px_s + kx) + ov.y;
    float y0f = floorf(py), x0f = floorf(pxf);
    float fy = py - y0f, fx = pxf - x0f;
    int iy0 = (int)y0f, ix0 = (int)x0f;
#pragma unroll
    for (int j = 0; j < 4; ++j) {
      int iy = iy0 + (j >> 1), ix = ix0 + (j & 1);
      float wy = (j >> 1) ? fy : 1.f - fy;
      float wx = (j & 1) ? fx : 1.f - fx;
      bool valid = (iy >= 0) && (iy < 64) && (ix >= 0) && (ix < 64);
      int iyc = min(max(iy, 0), 63), ixc = min(max(ix, 0), 63);
      wgt[j] = valid ? wy * wx : 0.f;
      p[j] = xb_base + ((size_t)(iyc + 1) * 66 + (ixc + 1)) * 128 + sub * 8;
    }
  };
  auto load_g2 = [&](const unsigned short** p, int g0, bf16x8 (*v)[4]) {
#pragma unroll
    for (int gg = 0; gg < 2; ++gg)
#pragma unroll
      for (int j = 0; j < 4; ++j)
        v[gg][j] = *(const bf16x8*)(p[j] + (g0 + gg) * 32);
  };
  auto store_g2 = [&](unsigned short* dst, int g0, const float* wgt, bf16x8 (*v)[4]) {
#pragma unroll
    for (int gg = 0; gg < 2; ++gg) {
      bf16x8 o;
#pragma unroll
      for (int j = 0; j < 8; ++j) {
        float s = fmaf(wgt[0], bf2f((unsigned short)v[gg][0][j]),
                  fmaf(wgt[1], bf2f((unsigned short)v[gg][1][j]),
                  fmaf(wgt[2], bf2f((unsigned short)v[gg][2][j]),
                       wgt[3] * bf2f((unsigned short)v[gg][3][j]))));
        o[j] = (short)f2bf(s);
      }
      *(bf16x8*)(dst + (g0 + gg) * 32) = o;
    }
  };
  auto mfma_half = [&](const unsigned short* buf, int tap, int kk0) {
#pragma unroll
    for (int kk = kk0; kk < kk0 + 2; ++kk) {
      bf16x8 af[4];
#pragma unroll
      for (int ms = 0; ms < 4; ++ms)
        af[ms] = *(const bf16x8*)(buf + (ms * 16 + m) * 136 + kk * 32 + quad * 8);
#pragma unroll
      for (int ns = 0; ns < 4; ++ns) {
        bf16x8 bfr = *(const bf16x8*)(wB + ((size_t)(tap * 16 + kk * 4 + quad) * 256 + nb + ns * 16 + m) * 8);
#pragma unroll
        for (int ms = 0; ms < 4; ++ms)
          acc[ms][ns] = __builtin_amdgcn_mfma_f32_16x16x32_bf16(af[ms], bfr, acc[ms][ns], 0, 0, 0);
      }
    }
  };

  // prologue: sample tap 0 into buf 0
  {
    float wgt[4]; const unsigned short* p[4]; bf16x8 v[2][4];
    sample_prep(0, wgt, p);
    unsigned short* dst = &At[0][px_s * 136 + sub * 8];
    load_g2(p, 0, v); store_g2(dst, 0, wgt, v);
    load_g2(p, 2, v); store_g2(dst, 2, wgt, v);
  }
#pragma unroll
  for (int tap = 0; tap < 9; ++tap) {
    __syncthreads();
    const unsigned short* cur = At[tap & 1];
    unsigned short* dst = &At[(tap + 1) & 1][px_s * 136 + sub * 8];
    if (tap < 8) {
      float wgt[4]; const unsigned short* p[4]; bf16x8 v[2][4];
      sample_prep(tap + 1, wgt, p);
      load_g2(p, 0, v);             // gathers in flight...
      mfma_half(cur, tap, 0);       // ...hidden behind 32 MFMAs
      store_g2(dst, 0, wgt, v);
      load_g2(p, 2, v);
      mfma_half(cur, tap, 2);
      store_g2(dst, 2, wgt, v);
    } else {
      mfma_half(cur, tap, 0);
      mfma_half(cur, tap, 2);
    }
  }

  // ---- epilogue: bias + BN partials; LDS transpose -> coalesced bf16 stores ----
  __syncthreads();                    // all waves done reading At
  unsigned short* yb = &At[0][0];     // 64 x 264 bf16 (33792 B)
#pragma unroll
  for (int ns = 0; ns < 4; ++ns) {
    int n = nb + ns * 16 + m;
    float bias = bdef[n];
    float s = 0.f, q = 0.f;
#pragma unroll
    for (int ms = 0; ms < 4; ++ms) {
#pragma unroll
      for (int r = 0; r < 4; ++r) {
        int px = ms * 16 + quad * 4 + r;
        float v = acc[ms][ns][r] + bias;
        yb[px * 264 + n] = f2bf(v);
        s += v;
        q += v * v;
      }
    }
    s += __shfl_xor(s, 16); s += __shfl_xor(s, 32);
    q += __shfl_xor(q, 16); q += __shfl_xor(q, 32);
    if (quad == 0) {
      partials[((size_t)blk * 256 + n) * 2 + 0] = s;
      partials[((size_t)blk * 256 + n) * 2 + 1] = q;
    }
  }
  __syncthreads();
  {
    unsigned short* grow = ymain + (size_t)(blk * 64 + px_s) * 256;
    const unsigned short* lrow = yb + px_s * 264;
#pragma unroll
    for (int k = 0; k < 8; ++k) {
      int n0 = k * 32 + sub * 8;      // 4 consecutive lanes -> one 64B line
      *(bf16x8*)(grow + n0) = *(const bf16x8*)(lrow + n0);
    }
  }
}

// ---------------- BN stats reduce ----------------
__global__ __launch_bounds__(64) void k_stats(const float* __restrict__ partials,
                                              const float* __restrict__ gamma,
                                              const float* __restrict__ beta,
                                              float* __restrict__ stats) {
  int ch = blockIdx.x;                // 256
  int L = threadIdx.x;                // 64
  float s = 0.f, q = 0.f;
#pragma unroll
  for (int i = 0; i < 8; ++i) {
    int row = i * 64 + L;
    s += partials[((size_t)row * 256 + ch) * 2 + 0];
    q += partials[((size_t)row * 256 + ch) * 2 + 1];
  }
#pragma unroll
  for (int d = 1; d < 64; d <<= 1) { s += __shfl_xor(s, d); q += __shfl_xor(q, d); }
  if (L == 0) {
    float mean = s * (1.f / 32768.f);
    float var = q * (1.f / 32768.f) - mean * mean;
    float inv = rsqrtf(var + 1e-5f);
    float A = gamma[ch] * inv;
    stats[ch * 2 + 0] = A;
    stats[ch * 2 + 1] = beta[ch] - mean * A;
  }
}

// ---------------- final: 1x1 shortcut MFMA + BN apply + ReLU + NCHW store ----------------
__global__ __launch_bounds__(256) void k_final(const unsigned short* __restrict__ xp,
                                               const unsigned short* __restrict__ wS,
                                               const unsigned short* __restrict__ ymain,
                                               const float* __restrict__ stats,
                                               const float* __restrict__ bsc,
                                               float* __restrict__ out) {
  int blk = blockIdx.x;               // 512 = b*64 + h
  int b = blk >> 6, h = blk & 63;
  int t = threadIdx.x;
  int lane = t & 63, wid = t >> 6;
  int m = lane & 15, quad = lane >> 4;
  __shared__ float tr[128 * 67];
  f32x4 acc[4][4];
#pragma unroll
  for (int i = 0; i < 4; ++i)
#pragma unroll
    for (int j = 0; j < 4; ++j) acc[i][j] = (f32x4){0.f, 0.f, 0.f, 0.f};
  const unsigned short* xrow = xp + ((size_t)(b * 66 + h + 1) * 66 + 1) * 128;
  int nb = wid * 64;
#pragma unroll
  for (int kk = 0; kk < 4; ++kk) {
    bf16x8 af[4];
#pragma unroll
    for (int ms = 0; ms < 4; ++ms)
      af[ms] = *(const bf16x8*)(xrow + (ms * 16 + m) * 128 + kk * 32 + quad * 8);
#pragma unroll
    for (int ns = 0; ns < 4; ++ns) {
      bf16x8 bfr = *(const bf16x8*)(wS + ((size_t)(kk * 4 + quad) * 256 + nb + ns * 16 + m) * 8);
#pragma unroll
      for (int ms = 0; ms < 4; ++ms)
        acc[ms][ns] = __builtin_amdgcn_mfma_f32_16x16x32_bf16(af[ms], bfr, acc[ms][ns], 0, 0, 0);
    }
  }
  for (int pass = 0; pass < 2; ++pass) {
    // phase A: waves owning this n-half park shortcut+bias into LDS
    if ((wid >> 1) == pass) {
#pragma unroll
      for (int ns = 0; ns < 4; ++ns) {
        int n = nb + ns * 16 + m;
        float bs = bsc[n];
        int nl = n - pass * 128;
#pragma unroll
        for (int ms = 0; ms < 4; ++ms)
#pragma unroll
          for (int r = 0; r < 4; ++r) {
            int px = ms * 16 + quad * 4 + r;
            tr[nl * 67 + px] = acc[ms][ns][r] + bs;
          }
      }
    }
    __syncthreads();
    // phase B: coalesced bf16 ymain read + BN + ReLU, in place
    {
      int nl = t & 127, g = t >> 7;
      int n = pass * 128 + nl;
      float A = stats[n * 2], Bc = stats[n * 2 + 1];
#pragma unroll 8
      for (int i = 0; i < 32; ++i) {
        int px = g * 32 + i;
        float ym = bf2f(ymain[(size_t)(blk * 64 + px) * 256 + n]);
        float* pt = &tr[nl * 67 + px];
        *pt = fmaxf(fmaf(ym, A, Bc) + *pt, 0.f);
      }
    }
    __syncthreads();
    // phase C: transpose-store, coalesced in w
    {
      int ww = t & 63, ng = t >> 6;
#pragma unroll 8
      for (int i = 0; i < 32; ++i) {
        int nl = ng * 32 + i;
        out[((size_t)(b * 256 + pass * 128 + nl) * 64 + h) * 64 + ww] = tr[nl * 67 + ww];
      }
    }
    __syncthreads();
  }
}

extern "C" void kernel_launch(void* const* d_in, const int* in_sizes, int n_in,
                              void* d_out, int out_size, void* d_ws, size_t ws_size,
                              hipStream_t stream) {
  const float* x     = (const float*)d_in[0];
  const float* w_off = (const float*)d_in[1];
  const float* b_off = (const float*)d_in[2];
  const float* w_def = (const float*)d_in[3];
  const float* b_def = (const float*)d_in[4];
  const float* gamma = (const float*)d_in[5];
  const float* beta  = (const float*)d_in[6];
  const float* w_sc  = (const float*)d_in[7];
  const float* b_sc  = (const float*)d_in[8];
  float* out = (float*)d_out;

  char* ws = (char*)d_ws;
  unsigned short* xpad  = (unsigned short*)(ws + OFF_XPAD);
  unsigned short* wB    = (unsigned short*)(ws + OFF_WB);
  unsigned short* wS    = (unsigned short*)(ws + OFF_WS2);
  unsigned short* wO    = (unsigned short*)(ws + OFF_WO);
  unsigned short* ymain = (unsigned short*)(ws + OFF_YM);
  float* partials       = (float*)(ws + OFF_PART);
  float* stats          = (float*)(ws + OFF_STAT);

  hipMemsetAsync(xpad, 0, SZ_XPAD, stream);
  k_prep_x<<<512, 256, 0, stream>>>(x, xpad);
  k_pack_w<<<1424, 256, 0, stream>>>(w_def, w_sc, w_off, wB, wS, wO);
  k_main<<<512, 256, 0, stream>>>(xpad, wB, wO, b_off, b_def, ymain, partials);
  k_stats<<<256, 64, 0, stream>>>(partials, gamma, beta, stats);
  k_final<<<512, 256, 0, stream>>>(xpad, wS, ymain, stats, b_sc, out);
}